// Round 15
// baseline (299.745 us; speedup 1.0000x reference)
//
#include <hip/hip_runtime.h>
#include <hip/hip_bf16.h>

typedef __attribute__((ext_vector_type(8))) short bf16x8;
typedef __attribute__((ext_vector_type(4))) float f32x4;
typedef __attribute__((ext_vector_type(4))) unsigned int u32x4;
typedef unsigned long long ull;

#define RT 128
#define NB (262144 / RT)
#define XSTR 32   // SINGLE DELTA vs r11 (was 40): row = 24 data + aug@24 + zeros 25..31

// LDS byte offsets — total 64,192 B <= 64KB so 2 blocks/CU can be resident
#define X_OFF 0          // x: [4][128][32] bf16    = 32768 B
#define O_OFF 32768      // o: [4][2][129][12] bf16 = 24768 B
#define Y_OFF 57536      // y: [2][128][12] bf16    =  6144 B
#define E_OFF 63680      // e: [128] f32            =   512 B
#define SMEM_BYTES 64192

// 3-VALU bf16 pair pack (round-6-verified; NO inline asm — asm cvt_pk proven
// poison in r5): ties-away rounding via +0x8000, then v_perm_b32 packs the
// two high halves: D[15:0]=bf16(lo), D[31:16]=bf16(hi).
__device__ __forceinline__ unsigned pk2(float lo, float hi) {
  union { float f; unsigned u; } a, b;
  a.f = lo; b.f = hi;
  return __builtin_amdgcn_perm(b.u + 0x8000u, a.u + 0x8000u, 0x07060302u);
}
__device__ __forceinline__ void unp4(ull v, float* d) {
  unsigned a = (unsigned)v, b = (unsigned)(v >> 32);
  union { unsigned u; float f; } x;
  x.u = a << 16;         d[0] = x.f;
  x.u = a & 0xffff0000u; d[1] = x.f;
  x.u = b << 16;         d[2] = x.f;
  x.u = b & 0xffff0000u; d[3] = x.f;
}
__device__ __forceinline__ bf16x8 mkfrag(unsigned w0, unsigned w1, unsigned w2, unsigned w3) {
  union { bf16x8 v; unsigned u[4]; } U;
  U.u[0] = w0; U.u[1] = w1; U.u[2] = w2; U.u[3] = w3;
  return U.v;
}
__device__ __forceinline__ f32x4 mfma16(bf16x8 a, bf16x8 b, f32x4 c) {
  return __builtin_amdgcn_mfma_f32_16x16x32_bf16(a, b, c, 0, 0, 0);
}

// ROUND-15 = ROUND-12 artifact, 4th submission (infra failures r12/r13/r14:
// dead pod 'rural-empty-tender-reply'; artifact has never executed).
// psi-16x16 structure (r8-verified arithmetic, r11-verified perf at 356us):
//   psi(16*mt + 4*g + r) = 32*(mt>>1) + 8*g + 4*(mt&1) + r
// applied to W1/W2 output columns and b2; hop is register-contiguous.
// r11 counters: VGPR 124, Occupancy 23% (1 block/CU), 49% stall. Hypothesis:
// LDS 72.7KB > 64KB boundary blocks the 2nd workgroup; this round shrinks
// LDS to 64,192 B with ZERO logic change (XSTR 40->32).
__global__ __launch_bounds__(512, 2) void rrsep(
    const float* __restrict__ y_real, const float* __restrict__ y_imag,
    const float* __restrict__ W1, const float* __restrict__ b1,
    const float* __restrict__ W2, const float* __restrict__ b2,
    const float* __restrict__ W3, const float* __restrict__ b3,
    float* __restrict__ out)
{
  __shared__ __align__(16) char smem[SMEM_BYTES];
  unsigned short* xs = (unsigned short*)(smem + X_OFF);
  unsigned short* os = (unsigned short*)(smem + O_OFF);
  unsigned short* ys = (unsigned short*)(smem + Y_OFF);
  float* es = (float*)(smem + E_OFF);

  const int tid  = (int)threadIdx.x;
  const int lane = tid & 63;
  const int w    = tid >> 6;     // wave 0..7
  const int p    = w >> 1;       // port
  const int c    = w & 1;        // channel
  const int q    = lane & 15;    // A/B row-col lane index
  const int g    = lane >> 4;    // k-group / C-row group
  const long r0  = (long)blockIdx.x * RT;

  // psi for A-frag rows (m' = 16mt + q) — stage-invariant
  int mpsi[4];
  #pragma unroll
  for (int mt = 0; mt < 4; ++mt)
    mpsi[mt] = 32*(mt>>1) + 8*(q>>2) + 4*(mt&1) + (q&3);

  // ---------------- prologue: coalesced load, normalize, init x ----------------
  {
    float* stg = (float*)smem;   // overlays x region before its first use
    if (tid < 384) {
      ((f32x4*)stg)[tid]          = ((const f32x4*)(y_real + r0 * 12))[tid];
      ((f32x4*)(stg + 1536))[tid] = ((const f32x4*)(y_imag + r0 * 12))[tid];
    }
    __syncthreads();
    float yv[24]; float ev = 0.f, inv = 0.f;
    if (tid < RT) {
      float acc = 0.f;
      #pragma unroll
      for (int l = 0; l < 12; ++l) {
        yv[l]      = stg[tid * 12 + l];
        yv[12 + l] = stg[1536 + tid * 12 + l];
        acc += yv[l] * yv[l] + yv[12 + l] * yv[12 + l];
      }
      ev  = sqrtf(acc * (1.f / 12.f));
      inv = 1.f / (ev + 1e-8f);
    }
    __syncthreads();   // all slab reads done before x overwrites the region
    if (tid < RT) {
      es[tid] = ev;
      unsigned pkw[12];
      #pragma unroll
      for (int j = 0; j < 12; ++j) pkw[j] = pk2(yv[2*j] * inv, yv[2*j+1] * inv);
      ull* yr0 = (ull*)(ys + (0 * RT + tid) * 12);
      yr0[0] = (ull)pkw[0] | ((ull)pkw[1] << 32);
      yr0[1] = (ull)pkw[2] | ((ull)pkw[3] << 32);
      yr0[2] = (ull)pkw[4] | ((ull)pkw[5] << 32);
      ull* yr1 = (ull*)(ys + (1 * RT + tid) * 12);
      yr1[0] = (ull)pkw[6]  | ((ull)pkw[7]  << 32);
      yr1[1] = (ull)pkw[8]  | ((ull)pkw[9]  << 32);
      yr1[2] = (ull)pkw[10] | ((ull)pkw[11] << 32);
      #pragma unroll
      for (int p2 = 0; p2 < 4; ++p2) {
        u32x4* xr = (u32x4*)(xs + (p2 * RT + tid) * XSTR);
        u32x4 t0; t0[0]=pkw[0]; t0[1]=pkw[1]; t0[2]=pkw[2]; t0[3]=pkw[3];
        u32x4 t1; t1[0]=pkw[4]; t1[1]=pkw[5]; t1[2]=pkw[6]; t1[3]=pkw[7];
        u32x4 t2; t2[0]=pkw[8]; t2[1]=pkw[9]; t2[2]=pkw[10]; t2[3]=pkw[11];
        u32x4 t3; t3[0]=pk2(1.f, 0.f); t3[1]=0u; t3[2]=0u; t3[3]=0u;  // aug x[24]=1, zeros 25..31
        xr[0]=t0; xr[1]=t1; xr[2]=t2; xr[3]=t3;
      }
    }
    __syncthreads();
  }

  #pragma unroll 1
  for (int s = 0; s < 3; ++s) {
    const int pc = (s * 4 + p) * 2 + c;
    const float* W1g = W1 + pc * 24 * 64;
    const float* b1g = b1 + pc * 64;
    const float* W2g = W2 + pc * 64 * 64;
    const float* b2g = b2 + pc * 64;
    const float* W3g = W3 + pc * 64 * 12;
    const float* b3g = b3 + pc * 12;

    // ---- W1 A-frags (psi on output cols, b1 folded at k=24): elem j <-> k=8g+j ----
    bf16x8 w1f[4];
    #pragma unroll
    for (int mt = 0; mt < 4; ++mt) {
      unsigned u[4];
      #pragma unroll
      for (int wq = 0; wq < 4; ++wq) {
        int k0 = 8*g + 2*wq;
        float v0 = (k0 < 24) ? W1g[k0*64 + mpsi[mt]] : ((k0 == 24) ? b1g[mpsi[mt]] : 0.f);
        float v1 = (k0+1 < 24) ? W1g[(k0+1)*64 + mpsi[mt]] : 0.f;   // k0+1 odd, never 24
        u[wq] = pk2(v0, v1);
      }
      w1f[mt] = mkfrag(u[0], u[1], u[2], u[3]);
    }
    // ---- W2 A-frags (input k actual, psi on output cols): k = 32kt+8g+j ----
    bf16x8 w2f[2][4];
    #pragma unroll
    for (int kt = 0; kt < 2; ++kt)
      #pragma unroll
      for (int mt = 0; mt < 4; ++mt) {
        unsigned u[4];
        #pragma unroll
        for (int wq = 0; wq < 4; ++wq) {
          int k0 = 32*kt + 8*g + 2*wq;
          u[wq] = pk2(W2g[k0*64 + mpsi[mt]], W2g[(k0+1)*64 + mpsi[mt]]);
        }
        w2f[kt][mt] = mkfrag(u[0], u[1], u[2], u[3]);
      }
    // ---- W3 A-frags (all actual; M=12 padded to 16 with zeros) ----
    bf16x8 w3f[2];
    #pragma unroll
    for (int kt = 0; kt < 2; ++kt) {
      unsigned u[4];
      #pragma unroll
      for (int wq = 0; wq < 4; ++wq) {
        int k0 = 32*kt + 8*g + 2*wq;
        float v0 = (q < 12) ? W3g[k0*12 + q]     : 0.f;
        float v1 = (q < 12) ? W3g[(k0+1)*12 + q] : 0.f;
        u[wq] = pk2(v0, v1);
      }
      w3f[kt] = mkfrag(u[0], u[1], u[2], u[3]);
    }
    // ---- biases as C-init (round-1-verified): C row = 4g+reg ----
    f32x4 b2f[4], b3f;
    #pragma unroll
    for (int mt = 0; mt < 4; ++mt) {
      #pragma unroll
      for (int r = 0; r < 4; ++r)
        b2f[mt][r] = b2g[32*(mt>>1) + 8*g + 4*(mt&1) + r];   // b2[psi(16mt+4g+r)]
    }
    #pragma unroll
    for (int r = 0; r < 4; ++r) {
      int m = 4*g + r;
      b3f[r] = (m < 12) ? b3g[m] : 0.f;
    }

    // ---------------- main: 8 chunks of 16 rows; unroll 2 for chunk-level ILP ----------------
    #pragma unroll 2
    for (int ch = 0; ch < 8; ++ch) {
      const int row = ch * 16 + q;
      bf16x8 xb = *(const bf16x8*)(xs + (p * RT + row) * XSTR + 8 * g);

      // mm1: H1psi^T = W1psi^T · [X|1]^T   (K=32 covers 24 data + aug + pad)
      f32x4 c1[4];
      #pragma unroll
      for (int mt = 0; mt < 4; ++mt) c1[mt] = mfma16(w1f[mt], xb, f32x4{0.f,0.f,0.f,0.f});

      // hop1: relu+pack contiguous C-regs; fr1[kt] elem 4a+r = c1[2kt+a][r]
      bf16x8 fr1[2];
      #pragma unroll
      for (int kt = 0; kt < 2; ++kt)
        fr1[kt] = mkfrag(
          pk2(fmaxf(c1[2*kt][0], 0.f),   fmaxf(c1[2*kt][1], 0.f)),
          pk2(fmaxf(c1[2*kt][2], 0.f),   fmaxf(c1[2*kt][3], 0.f)),
          pk2(fmaxf(c1[2*kt+1][0], 0.f), fmaxf(c1[2*kt+1][1], 0.f)),
          pk2(fmaxf(c1[2*kt+1][2], 0.f), fmaxf(c1[2*kt+1][3], 0.f)));

      // mm2: bias via C-init, K=64 as two k-windows
      f32x4 c2[4];
      #pragma unroll
      for (int mt = 0; mt < 4; ++mt) {
        c2[mt] = mfma16(w2f[0][mt], fr1[0], b2f[mt]);
        c2[mt] = mfma16(w2f[1][mt], fr1[1], c2[mt]);
      }
      // hop2
      bf16x8 fr2[2];
      #pragma unroll
      for (int kt = 0; kt < 2; ++kt)
        fr2[kt] = mkfrag(
          pk2(fmaxf(c2[2*kt][0], 0.f),   fmaxf(c2[2*kt][1], 0.f)),
          pk2(fmaxf(c2[2*kt][2], 0.f),   fmaxf(c2[2*kt][3], 0.f)),
          pk2(fmaxf(c2[2*kt+1][0], 0.f), fmaxf(c2[2*kt+1][1], 0.f)),
          pk2(fmaxf(c2[2*kt+1][2], 0.f), fmaxf(c2[2*kt+1][3], 0.f)));

      // mm3: O^T (12 valid rows), bias via C-init
      f32x4 c3 = mfma16(w3f[0], fr2[0], b3f);
      c3 = mfma16(w3f[1], fr2[1], c3);

      // o-write: C reg r = out-feat 4g+r at data row `row`; g<3 covers feats 0..11
      if (g < 3) {
        unsigned k0 = pk2(c3[0], c3[1]);
        unsigned k1 = pk2(c3[2], c3[3]);
        *(ull*)(os + ((p * 2 + c) * 129 + row) * 12 + 4 * g) = (ull)k0 | ((ull)k1 << 32);
      }
    }
    __syncthreads();

    // ---------------- residual combine (round-3-verified, unchanged) ----------------
    {
      const int r = tid >> 2, pp = tid & 3;
      float sum[24], own[24], yn[24];
      #pragma unroll
      for (int k = 0; k < 24; ++k) sum[k] = 0.f;
      #pragma unroll
      for (int pp2 = 0; pp2 < 4; ++pp2)
        #pragma unroll
        for (int cc = 0; cc < 2; ++cc) {
          const ull* orow = (const ull*)(os + ((pp2 * 2 + cc) * 129 + r) * 12);
          float t[12];
          unp4(orow[0], t); unp4(orow[1], t + 4); unp4(orow[2], t + 8);
          #pragma unroll
          for (int l = 0; l < 12; ++l) sum[cc * 12 + l] += t[l];
        }
      #pragma unroll
      for (int cc = 0; cc < 2; ++cc) {
        const ull* orow = (const ull*)(os + ((pp * 2 + cc) * 129 + r) * 12);
        unp4(orow[0], own + cc * 12); unp4(orow[1], own + cc * 12 + 4); unp4(orow[2], own + cc * 12 + 8);
        const ull* yrow = (const ull*)(ys + (cc * RT + r) * 12);
        unp4(yrow[0], yn + cc * 12); unp4(yrow[1], yn + cc * 12 + 4); unp4(yrow[2], yn + cc * 12 + 8);
      }
      if (s < 2) {
        unsigned xw[12];
        #pragma unroll
        for (int j = 0; j < 12; ++j) {
          float v0 = own[2*j]   + (yn[2*j]   - sum[2*j]);
          float v1 = own[2*j+1] + (yn[2*j+1] - sum[2*j+1]);
          xw[j] = pk2(v0, v1);
        }
        u32x4* xr = (u32x4*)(xs + (pp * RT + r) * XSTR);
        u32x4 t0; t0[0]=xw[0]; t0[1]=xw[1]; t0[2]=xw[2];  t0[3]=xw[3];
        u32x4 t1; t1[0]=xw[4]; t1[1]=xw[5]; t1[2]=xw[6];  t1[3]=xw[7];
        u32x4 t2; t2[0]=xw[8]; t2[1]=xw[9]; t2[2]=xw[10]; t2[3]=xw[11];
        xr[0]=t0; xr[1]=t1; xr[2]=t2;
        __syncthreads();
      } else {
        const float ev = es[r];
        float vals[24];
        #pragma unroll
        for (int l = 0; l < 12; ++l) {
          vals[2*l]   = (own[l]      + yn[l]      - sum[l])      * ev;
          vals[2*l+1] = (own[12 + l] + yn[12 + l] - sum[12 + l]) * ev;
        }
        __syncthreads();                       // all o/y/e reads done
        float* vstg = (float*)smem;            // overlays x/o regions (49152 B fits)
        f32x4* vw = (f32x4*)(vstg + r * 96 + pp * 24);
        #pragma unroll
        for (int i = 0; i < 6; ++i) {
          f32x4 t; t[0]=vals[4*i]; t[1]=vals[4*i+1]; t[2]=vals[4*i+2]; t[3]=vals[4*i+3];
          vw[i] = t;
        }
        __syncthreads();
        const f32x4* vp = (const f32x4*)vstg;
        f32x4* og = (f32x4*)(out + r0 * 96);
        #pragma unroll
        for (int i = 0; i < 6; ++i) og[tid + 512 * i] = vp[tid + 512 * i];
      }
    }
  }
}

extern "C" void kernel_launch(void* const* d_in, const int* in_sizes, int n_in,
                              void* d_out, int out_size, void* d_ws, size_t ws_size,
                              hipStream_t stream) {
  const float* y_real = (const float*)d_in[0];
  const float* y_imag = (const float*)d_in[1];
  const float* W1 = (const float*)d_in[2];
  const float* b1 = (const float*)d_in[3];
  const float* W2 = (const float*)d_in[4];
  const float* b2 = (const float*)d_in[5];
  const float* W3 = (const float*)d_in[6];
  const float* b3 = (const float*)d_in[7];
  float* out = (float*)d_out;

  hipLaunchKernelGGL(rrsep, dim3(NB), dim3(512), 0, stream,
                     y_real, y_imag, W1, b1, W2, b2, W3, b3, out);
}

// Round 16
// 292.689 us; speedup vs baseline: 1.0241x; 1.0241x over previous
//
#include <hip/hip_runtime.h>
#include <hip/hip_bf16.h>

typedef __attribute__((ext_vector_type(8))) short bf16x8;
typedef __attribute__((ext_vector_type(4))) float f32x4;
typedef __attribute__((ext_vector_type(4))) unsigned int u32x4;
typedef unsigned long long ull;

#define RT 128
#define NB (262144 / RT)
#define XSTR 32

// LDS byte offsets — 64,192 B/block; 2 blocks/CU = 128.4KB <= 160KB
#define X_OFF 0          // x: [4][128][32] bf16    = 32768 B
#define O_OFF 32768      // o: [4][2][129][12] bf16 = 24768 B
#define Y_OFF 57536      // y: [2][128][12] bf16    =  6144 B
#define E_OFF 63680      // e: [128] f32            =   512 B
#define SMEM_BYTES 64192

// 3-VALU bf16 pair pack (r6-verified; NO inline asm — asm cvt_pk = poison, r5).
__device__ __forceinline__ unsigned pk2(float lo, float hi) {
  union { float f; unsigned u; } a, b;
  a.f = lo; b.f = hi;
  return __builtin_amdgcn_perm(b.u + 0x8000u, a.u + 0x8000u, 0x07060302u);
}
__device__ __forceinline__ void unp4(ull v, float* d) {
  unsigned a = (unsigned)v, b = (unsigned)(v >> 32);
  union { unsigned u; float f; } x;
  x.u = a << 16;         d[0] = x.f;
  x.u = a & 0xffff0000u; d[1] = x.f;
  x.u = b << 16;         d[2] = x.f;
  x.u = b & 0xffff0000u; d[3] = x.f;
}
__device__ __forceinline__ bf16x8 mkfrag(unsigned w0, unsigned w1, unsigned w2, unsigned w3) {
  union { bf16x8 v; unsigned u[4]; } U;
  U.u[0] = w0; U.u[1] = w1; U.u[2] = w2; U.u[3] = w3;
  return U.v;
}
__device__ __forceinline__ f32x4 mfma16(bf16x8 a, bf16x8 b, f32x4 c) {
  return __builtin_amdgcn_mfma_f32_16x16x32_bf16(a, b, c, 0, 0, 0);
}

// ROUND-16: 256-thread blocks for cross-block phase overlap.
// r15 falsified the 64KB-LDS hypothesis -> residency is register-locked
// (~190 unified regs/wave: r8 showed 64 arch + accum at forced 128-cap with
// spill). 2x512-thread blocks can never co-reside; 2x256-thread blocks CAN
// (8 waves/CU = 2/SIMD at <=256 regs). Wave = port p (4 waves); channels
// sequential (#pragma unroll 1 -> one 76-reg weight set live). Independent
// blocks desynchronize stage phases: one block's weight-load/combine hides
// under the other's MFMA chunks. psi-16x16 arithmetic unchanged (r8-verified):
//   psi(16*mt + 4*g + r) = 32*(mt>>1) + 8*g + 4*(mt&1) + r
__global__ __launch_bounds__(256, 2) void rrsep(
    const float* __restrict__ y_real, const float* __restrict__ y_imag,
    const float* __restrict__ W1, const float* __restrict__ b1,
    const float* __restrict__ W2, const float* __restrict__ b2,
    const float* __restrict__ W3, const float* __restrict__ b3,
    float* __restrict__ out)
{
  __shared__ __align__(16) char smem[SMEM_BYTES];
  unsigned short* xs = (unsigned short*)(smem + X_OFF);
  unsigned short* os = (unsigned short*)(smem + O_OFF);
  unsigned short* ys = (unsigned short*)(smem + Y_OFF);
  float* es = (float*)(smem + E_OFF);

  const int tid  = (int)threadIdx.x;
  const int lane = tid & 63;
  const int p    = tid >> 6;     // wave 0..3 = port
  const int q    = lane & 15;
  const int g    = lane >> 4;
  const long r0  = (long)blockIdx.x * RT;

  // psi for A-frag rows (m' = 16mt + q) — stage-invariant
  int mpsi[4];
  #pragma unroll
  for (int mt = 0; mt < 4; ++mt)
    mpsi[mt] = 32*(mt>>1) + 8*(q>>2) + 4*(mt&1) + (q&3);

  // ---------------- prologue: coalesced load, normalize, init x ----------------
  {
    float* stg = (float*)smem;   // overlays x region before its first use
    for (int i = tid; i < 384; i += 256) {
      ((f32x4*)stg)[i]          = ((const f32x4*)(y_real + r0 * 12))[i];
      ((f32x4*)(stg + 1536))[i] = ((const f32x4*)(y_imag + r0 * 12))[i];
    }
    __syncthreads();
    float yv[24]; float ev = 0.f, inv = 0.f;
    if (tid < RT) {
      float acc = 0.f;
      #pragma unroll
      for (int l = 0; l < 12; ++l) {
        yv[l]      = stg[tid * 12 + l];
        yv[12 + l] = stg[1536 + tid * 12 + l];
        acc += yv[l] * yv[l] + yv[12 + l] * yv[12 + l];
      }
      ev  = sqrtf(acc * (1.f / 12.f));
      inv = 1.f / (ev + 1e-8f);
    }
    __syncthreads();   // all slab reads done before x overwrites the region
    if (tid < RT) {
      es[tid] = ev;
      unsigned pkw[12];
      #pragma unroll
      for (int j = 0; j < 12; ++j) pkw[j] = pk2(yv[2*j] * inv, yv[2*j+1] * inv);
      ull* yr0 = (ull*)(ys + (0 * RT + tid) * 12);
      yr0[0] = (ull)pkw[0] | ((ull)pkw[1] << 32);
      yr0[1] = (ull)pkw[2] | ((ull)pkw[3] << 32);
      yr0[2] = (ull)pkw[4] | ((ull)pkw[5] << 32);
      ull* yr1 = (ull*)(ys + (1 * RT + tid) * 12);
      yr1[0] = (ull)pkw[6]  | ((ull)pkw[7]  << 32);
      yr1[1] = (ull)pkw[8]  | ((ull)pkw[9]  << 32);
      yr1[2] = (ull)pkw[10] | ((ull)pkw[11] << 32);
      #pragma unroll
      for (int p2 = 0; p2 < 4; ++p2) {
        u32x4* xr = (u32x4*)(xs + (p2 * RT + tid) * XSTR);
        u32x4 t0; t0[0]=pkw[0]; t0[1]=pkw[1]; t0[2]=pkw[2]; t0[3]=pkw[3];
        u32x4 t1; t1[0]=pkw[4]; t1[1]=pkw[5]; t1[2]=pkw[6]; t1[3]=pkw[7];
        u32x4 t2; t2[0]=pkw[8]; t2[1]=pkw[9]; t2[2]=pkw[10]; t2[3]=pkw[11];
        u32x4 t3; t3[0]=pk2(1.f, 0.f); t3[1]=0u; t3[2]=0u; t3[3]=0u;  // aug x[24]=1
        xr[0]=t0; xr[1]=t1; xr[2]=t2; xr[3]=t3;
      }
    }
    __syncthreads();
  }

  #pragma unroll 1
  for (int s = 0; s < 3; ++s) {
    // ---------- channel-sequential main phase: one weight set live ----------
    #pragma unroll 1
    for (int cc = 0; cc < 2; ++cc) {
      const int pc = (s * 4 + p) * 2 + cc;
      const float* W1g = W1 + pc * 24 * 64;
      const float* b1g = b1 + pc * 64;
      const float* W2g = W2 + pc * 64 * 64;
      const float* b2g = b2 + pc * 64;
      const float* W3g = W3 + pc * 64 * 12;
      const float* b3g = b3 + pc * 12;

      // W1 A-frags (psi on output cols, b1 folded at k=24)
      bf16x8 w1f[4];
      #pragma unroll
      for (int mt = 0; mt < 4; ++mt) {
        unsigned u[4];
        #pragma unroll
        for (int wq = 0; wq < 4; ++wq) {
          int k0 = 8*g + 2*wq;
          float v0 = (k0 < 24) ? W1g[k0*64 + mpsi[mt]] : ((k0 == 24) ? b1g[mpsi[mt]] : 0.f);
          float v1 = (k0+1 < 24) ? W1g[(k0+1)*64 + mpsi[mt]] : 0.f;
          u[wq] = pk2(v0, v1);
        }
        w1f[mt] = mkfrag(u[0], u[1], u[2], u[3]);
      }
      // W2 A-frags (input k actual, psi on output cols)
      bf16x8 w2f[2][4];
      #pragma unroll
      for (int kt = 0; kt < 2; ++kt)
        #pragma unroll
        for (int mt = 0; mt < 4; ++mt) {
          unsigned u[4];
          #pragma unroll
          for (int wq = 0; wq < 4; ++wq) {
            int k0 = 32*kt + 8*g + 2*wq;
            u[wq] = pk2(W2g[k0*64 + mpsi[mt]], W2g[(k0+1)*64 + mpsi[mt]]);
          }
          w2f[kt][mt] = mkfrag(u[0], u[1], u[2], u[3]);
        }
      // W3 A-frags (M=12 padded to 16 with zeros)
      bf16x8 w3f[2];
      #pragma unroll
      for (int kt = 0; kt < 2; ++kt) {
        unsigned u[4];
        #pragma unroll
        for (int wq = 0; wq < 4; ++wq) {
          int k0 = 32*kt + 8*g + 2*wq;
          float v0 = (q < 12) ? W3g[k0*12 + q]     : 0.f;
          float v1 = (q < 12) ? W3g[(k0+1)*12 + q] : 0.f;
          u[wq] = pk2(v0, v1);
        }
        w3f[kt] = mkfrag(u[0], u[1], u[2], u[3]);
      }
      // biases as C-init: C row = 4g+reg
      f32x4 b2f[4], b3f;
      #pragma unroll
      for (int mt = 0; mt < 4; ++mt) {
        #pragma unroll
        for (int r = 0; r < 4; ++r)
          b2f[mt][r] = b2g[32*(mt>>1) + 8*g + 4*(mt&1) + r];   // b2[psi(16mt+4g+r)]
      }
      #pragma unroll
      for (int r = 0; r < 4; ++r) {
        int m = 4*g + r;
        b3f[r] = (m < 12) ? b3g[m] : 0.f;
      }

      // main: 8 chunks of 16 rows; unroll 2 for chunk-level ILP (r11-verified)
      #pragma unroll 2
      for (int ch = 0; ch < 8; ++ch) {
        const int row = ch * 16 + q;
        bf16x8 xb = *(const bf16x8*)(xs + (p * RT + row) * XSTR + 8 * g);

        f32x4 c1[4];
        #pragma unroll
        for (int mt = 0; mt < 4; ++mt) c1[mt] = mfma16(w1f[mt], xb, f32x4{0.f,0.f,0.f,0.f});

        bf16x8 fr1[2];
        #pragma unroll
        for (int kt = 0; kt < 2; ++kt)
          fr1[kt] = mkfrag(
            pk2(fmaxf(c1[2*kt][0], 0.f),   fmaxf(c1[2*kt][1], 0.f)),
            pk2(fmaxf(c1[2*kt][2], 0.f),   fmaxf(c1[2*kt][3], 0.f)),
            pk2(fmaxf(c1[2*kt+1][0], 0.f), fmaxf(c1[2*kt+1][1], 0.f)),
            pk2(fmaxf(c1[2*kt+1][2], 0.f), fmaxf(c1[2*kt+1][3], 0.f)));

        f32x4 c2[4];
        #pragma unroll
        for (int mt = 0; mt < 4; ++mt) {
          c2[mt] = mfma16(w2f[0][mt], fr1[0], b2f[mt]);
          c2[mt] = mfma16(w2f[1][mt], fr1[1], c2[mt]);
        }
        bf16x8 fr2[2];
        #pragma unroll
        for (int kt = 0; kt < 2; ++kt)
          fr2[kt] = mkfrag(
            pk2(fmaxf(c2[2*kt][0], 0.f),   fmaxf(c2[2*kt][1], 0.f)),
            pk2(fmaxf(c2[2*kt][2], 0.f),   fmaxf(c2[2*kt][3], 0.f)),
            pk2(fmaxf(c2[2*kt+1][0], 0.f), fmaxf(c2[2*kt+1][1], 0.f)),
            pk2(fmaxf(c2[2*kt+1][2], 0.f), fmaxf(c2[2*kt+1][3], 0.f)));

        f32x4 c3 = mfma16(w3f[0], fr2[0], b3f);
        c3 = mfma16(w3f[1], fr2[1], c3);

        if (g < 3) {
          unsigned k0 = pk2(c3[0], c3[1]);
          unsigned k1 = pk2(c3[2], c3[3]);
          *(ull*)(os + ((p * 2 + cc) * 129 + row) * 12 + 4 * g) = (ull)k0 | ((ull)k1 << 32);
        }
      }
    }
    __syncthreads();

    // ------- residual combine: 512 (r,pp) units over 256 threads, 2/thread -------
    if (s < 2) {
      #pragma unroll
      for (int ui = 0; ui < 2; ++ui) {
        const int u2 = tid + 256 * ui;
        const int r = u2 >> 2, pp = u2 & 3;
        float sum[24], own[24], yn[24];
        #pragma unroll
        for (int k = 0; k < 24; ++k) sum[k] = 0.f;
        #pragma unroll
        for (int pp2 = 0; pp2 < 4; ++pp2)
          #pragma unroll
          for (int c2i = 0; c2i < 2; ++c2i) {
            const ull* orow = (const ull*)(os + ((pp2 * 2 + c2i) * 129 + r) * 12);
            float t[12];
            unp4(orow[0], t); unp4(orow[1], t + 4); unp4(orow[2], t + 8);
            #pragma unroll
            for (int l = 0; l < 12; ++l) sum[c2i * 12 + l] += t[l];
          }
        #pragma unroll
        for (int c2i = 0; c2i < 2; ++c2i) {
          const ull* orow = (const ull*)(os + ((pp * 2 + c2i) * 129 + r) * 12);
          unp4(orow[0], own + c2i*12); unp4(orow[1], own + c2i*12 + 4); unp4(orow[2], own + c2i*12 + 8);
          const ull* yrow = (const ull*)(ys + (c2i * RT + r) * 12);
          unp4(yrow[0], yn + c2i*12); unp4(yrow[1], yn + c2i*12 + 4); unp4(yrow[2], yn + c2i*12 + 8);
        }
        unsigned xw[12];
        #pragma unroll
        for (int j = 0; j < 12; ++j) {
          float v0 = own[2*j]   + (yn[2*j]   - sum[2*j]);
          float v1 = own[2*j+1] + (yn[2*j+1] - sum[2*j+1]);
          xw[j] = pk2(v0, v1);
        }
        u32x4* xr = (u32x4*)(xs + (pp * RT + r) * XSTR);
        u32x4 t0; t0[0]=xw[0]; t0[1]=xw[1]; t0[2]=xw[2];  t0[3]=xw[3];
        u32x4 t1; t1[0]=xw[4]; t1[1]=xw[5]; t1[2]=xw[6];  t1[3]=xw[7];
        u32x4 t2; t2[0]=xw[8]; t2[1]=xw[9]; t2[2]=xw[10]; t2[3]=xw[11];
        xr[0]=t0; xr[1]=t1; xr[2]=t2;
      }
      __syncthreads();
    } else {
      float vals2[2][24];
      #pragma unroll
      for (int ui = 0; ui < 2; ++ui) {
        const int u2 = tid + 256 * ui;
        const int r = u2 >> 2, pp = u2 & 3;
        float sum[24], own[24], yn[24];
        #pragma unroll
        for (int k = 0; k < 24; ++k) sum[k] = 0.f;
        #pragma unroll
        for (int pp2 = 0; pp2 < 4; ++pp2)
          #pragma unroll
          for (int c2i = 0; c2i < 2; ++c2i) {
            const ull* orow = (const ull*)(os + ((pp2 * 2 + c2i) * 129 + r) * 12);
            float t[12];
            unp4(orow[0], t); unp4(orow[1], t + 4); unp4(orow[2], t + 8);
            #pragma unroll
            for (int l = 0; l < 12; ++l) sum[c2i * 12 + l] += t[l];
          }
        #pragma unroll
        for (int c2i = 0; c2i < 2; ++c2i) {
          const ull* orow = (const ull*)(os + ((pp * 2 + c2i) * 129 + r) * 12);
          unp4(orow[0], own + c2i*12); unp4(orow[1], own + c2i*12 + 4); unp4(orow[2], own + c2i*12 + 8);
          const ull* yrow = (const ull*)(ys + (c2i * RT + r) * 12);
          unp4(yrow[0], yn + c2i*12); unp4(yrow[1], yn + c2i*12 + 4); unp4(yrow[2], yn + c2i*12 + 8);
        }
        const float ev = es[r];
        #pragma unroll
        for (int l = 0; l < 12; ++l) {
          vals2[ui][2*l]   = (own[l]      + yn[l]      - sum[l])      * ev;
          vals2[ui][2*l+1] = (own[12 + l] + yn[12 + l] - sum[12 + l]) * ev;
        }
      }
      __syncthreads();                       // all o/y/e reads done
      float* vstg = (float*)smem;            // overlays x/o regions
      #pragma unroll
      for (int ui = 0; ui < 2; ++ui) {
        const int u2 = tid + 256 * ui;
        f32x4* vw = (f32x4*)(vstg + (u2 >> 2) * 96 + (u2 & 3) * 24);
        #pragma unroll
        for (int i = 0; i < 6; ++i) {
          f32x4 t;
          t[0]=vals2[ui][4*i]; t[1]=vals2[ui][4*i+1]; t[2]=vals2[ui][4*i+2]; t[3]=vals2[ui][4*i+3];
          vw[i] = t;
        }
      }
      __syncthreads();
      const f32x4* vp = (const f32x4*)vstg;
      f32x4* og = (f32x4*)(out + r0 * 96);
      #pragma unroll
      for (int i = 0; i < 12; ++i) og[tid + 256 * i] = vp[tid + 256 * i];
    }
  }
}

extern "C" void kernel_launch(void* const* d_in, const int* in_sizes, int n_in,
                              void* d_out, int out_size, void* d_ws, size_t ws_size,
                              hipStream_t stream) {
  const float* y_real = (const float*)d_in[0];
  const float* y_imag = (const float*)d_in[1];
  const float* W1 = (const float*)d_in[2];
  const float* b1 = (const float*)d_in[3];
  const float* W2 = (const float*)d_in[4];
  const float* b2 = (const float*)d_in[5];
  const float* W3 = (const float*)d_in[6];
  const float* b3 = (const float*)d_in[7];
  float* out = (float*)d_out;

  hipLaunchKernelGGL(rrsep, dim3(NB), dim3(256), 0, stream,
                     y_real, y_imag, W1, b1, W2, b2, W3, b3, out);
}

// Round 17
// 284.307 us; speedup vs baseline: 1.0543x; 1.0295x over previous
//
#include <hip/hip_runtime.h>
#include <hip/hip_bf16.h>

typedef __attribute__((ext_vector_type(8))) short bf16x8;
typedef __attribute__((ext_vector_type(4))) float f32x4;
typedef __attribute__((ext_vector_type(4))) unsigned int u32x4;
typedef unsigned long long ull;

#define RT 128
#define NB (262144 / RT)
#define XSTR 32

// LDS byte offsets — 88,960 B (1 block/CU; residency is register-locked anyway, r15/r16)
#define X_OFF 0          // x: [4][128][32] bf16    = 32768 B
#define O_OFF 32768      // o: [4][2][129][12] f32  = 49536 B   (ROUND-17: was bf16)
#define Y_OFF 82304      // y: [2][128][12] bf16    =  6144 B
#define E_OFF 88448      // e: [128] f32            =   512 B
#define SMEM_BYTES 88960

// RNE 3-VALU pack (r6-verified) — weights / state / prologue keep full rounding.
__device__ __forceinline__ unsigned pk2(float lo, float hi) {
  union { float f; unsigned u; } a, b;
  a.f = lo; b.f = hi;
  return __builtin_amdgcn_perm(b.u + 0x8000u, a.u + 0x8000u, 0x07060302u);
}
// ROUND-17: truncating 1-VALU pack for inter-layer activations only (hop1/hop2).
// <=1 ulp error vs RNE's 0.5 ulp; saves 2 ops per pack.
__device__ __forceinline__ unsigned pk2t(float lo, float hi) {
  union { float f; unsigned u; } a, b;
  a.f = lo; b.f = hi;
  return __builtin_amdgcn_perm(b.u, a.u, 0x07060302u);
}
__device__ __forceinline__ void unp4(ull v, float* d) {
  unsigned a = (unsigned)v, b = (unsigned)(v >> 32);
  union { unsigned u; float f; } x;
  x.u = a << 16;         d[0] = x.f;
  x.u = a & 0xffff0000u; d[1] = x.f;
  x.u = b << 16;         d[2] = x.f;
  x.u = b & 0xffff0000u; d[3] = x.f;
}
__device__ __forceinline__ bf16x8 mkfrag(unsigned w0, unsigned w1, unsigned w2, unsigned w3) {
  union { bf16x8 v; unsigned u[4]; } U;
  U.u[0] = w0; U.u[1] = w1; U.u[2] = w2; U.u[3] = w3;
  return U.v;
}
__device__ __forceinline__ f32x4 mfma16(bf16x8 a, bf16x8 b, f32x4 c) {
  return __builtin_amdgcn_mfma_f32_16x16x32_bf16(a, b, c, 0, 0, 0);
}

// ROUND-17: r15 base (512-thread, psi-16x16, unroll-2 chunks; 299.7us bench /
// 350us prof). r16 falsified phase-desync (2x256-thread co-resident, dur
// unchanged) -> stall is intra-chain; lever = fewer VALU instructions.
// Deltas: (1) o_lds stored f32 (kills unp4 in combine + pk2 in o-write;
// spends free LDS, residency unaffected), (2) pk2t truncating pack on hops.
//   psi(16*mt + 4*g + r) = 32*(mt>>1) + 8*g + 4*(mt&1) + r
__global__ __launch_bounds__(512, 2) void rrsep(
    const float* __restrict__ y_real, const float* __restrict__ y_imag,
    const float* __restrict__ W1, const float* __restrict__ b1,
    const float* __restrict__ W2, const float* __restrict__ b2,
    const float* __restrict__ W3, const float* __restrict__ b3,
    float* __restrict__ out)
{
  __shared__ __align__(16) char smem[SMEM_BYTES];
  unsigned short* xs = (unsigned short*)(smem + X_OFF);
  float*          os = (float*)(smem + O_OFF);
  unsigned short* ys = (unsigned short*)(smem + Y_OFF);
  float*          es = (float*)(smem + E_OFF);

  const int tid  = (int)threadIdx.x;
  const int lane = tid & 63;
  const int w    = tid >> 6;     // wave 0..7
  const int p    = w >> 1;       // port
  const int c    = w & 1;        // channel
  const int q    = lane & 15;
  const int g    = lane >> 4;
  const long r0  = (long)blockIdx.x * RT;

  // psi for A-frag rows (m' = 16mt + q) — stage-invariant
  int mpsi[4];
  #pragma unroll
  for (int mt = 0; mt < 4; ++mt)
    mpsi[mt] = 32*(mt>>1) + 8*(q>>2) + 4*(mt&1) + (q&3);

  // ---------------- prologue: coalesced load, normalize, init x ----------------
  {
    float* stg = (float*)smem;   // overlays x region before its first use
    if (tid < 384) {
      ((f32x4*)stg)[tid]          = ((const f32x4*)(y_real + r0 * 12))[tid];
      ((f32x4*)(stg + 1536))[tid] = ((const f32x4*)(y_imag + r0 * 12))[tid];
    }
    __syncthreads();
    float yv[24]; float ev = 0.f, inv = 0.f;
    if (tid < RT) {
      float acc = 0.f;
      #pragma unroll
      for (int l = 0; l < 12; ++l) {
        yv[l]      = stg[tid * 12 + l];
        yv[12 + l] = stg[1536 + tid * 12 + l];
        acc += yv[l] * yv[l] + yv[12 + l] * yv[12 + l];
      }
      ev  = sqrtf(acc * (1.f / 12.f));
      inv = 1.f / (ev + 1e-8f);
    }
    __syncthreads();   // all slab reads done before x overwrites the region
    if (tid < RT) {
      es[tid] = ev;
      unsigned pkw[12];
      #pragma unroll
      for (int j = 0; j < 12; ++j) pkw[j] = pk2(yv[2*j] * inv, yv[2*j+1] * inv);
      ull* yr0 = (ull*)(ys + (0 * RT + tid) * 12);
      yr0[0] = (ull)pkw[0] | ((ull)pkw[1] << 32);
      yr0[1] = (ull)pkw[2] | ((ull)pkw[3] << 32);
      yr0[2] = (ull)pkw[4] | ((ull)pkw[5] << 32);
      ull* yr1 = (ull*)(ys + (1 * RT + tid) * 12);
      yr1[0] = (ull)pkw[6]  | ((ull)pkw[7]  << 32);
      yr1[1] = (ull)pkw[8]  | ((ull)pkw[9]  << 32);
      yr1[2] = (ull)pkw[10] | ((ull)pkw[11] << 32);
      #pragma unroll
      for (int p2 = 0; p2 < 4; ++p2) {
        u32x4* xr = (u32x4*)(xs + (p2 * RT + tid) * XSTR);
        u32x4 t0; t0[0]=pkw[0]; t0[1]=pkw[1]; t0[2]=pkw[2]; t0[3]=pkw[3];
        u32x4 t1; t1[0]=pkw[4]; t1[1]=pkw[5]; t1[2]=pkw[6]; t1[3]=pkw[7];
        u32x4 t2; t2[0]=pkw[8]; t2[1]=pkw[9]; t2[2]=pkw[10]; t2[3]=pkw[11];
        u32x4 t3; t3[0]=pk2(1.f, 0.f); t3[1]=0u; t3[2]=0u; t3[3]=0u;  // aug x[24]=1
        xr[0]=t0; xr[1]=t1; xr[2]=t2; xr[3]=t3;
      }
    }
    __syncthreads();
  }

  #pragma unroll 1
  for (int s = 0; s < 3; ++s) {
    const int pc = (s * 4 + p) * 2 + c;
    const float* W1g = W1 + pc * 24 * 64;
    const float* b1g = b1 + pc * 64;
    const float* W2g = W2 + pc * 64 * 64;
    const float* b2g = b2 + pc * 64;
    const float* W3g = W3 + pc * 64 * 12;
    const float* b3g = b3 + pc * 12;

    // ---- W1 A-frags (psi on output cols, b1 folded at k=24): elem j <-> k=8g+j ----
    bf16x8 w1f[4];
    #pragma unroll
    for (int mt = 0; mt < 4; ++mt) {
      unsigned u[4];
      #pragma unroll
      for (int wq = 0; wq < 4; ++wq) {
        int k0 = 8*g + 2*wq;
        float v0 = (k0 < 24) ? W1g[k0*64 + mpsi[mt]] : ((k0 == 24) ? b1g[mpsi[mt]] : 0.f);
        float v1 = (k0+1 < 24) ? W1g[(k0+1)*64 + mpsi[mt]] : 0.f;   // k0+1 odd, never 24
        u[wq] = pk2(v0, v1);
      }
      w1f[mt] = mkfrag(u[0], u[1], u[2], u[3]);
    }
    // ---- W2 A-frags (input k actual, psi on output cols): k = 32kt+8g+j ----
    bf16x8 w2f[2][4];
    #pragma unroll
    for (int kt = 0; kt < 2; ++kt)
      #pragma unroll
      for (int mt = 0; mt < 4; ++mt) {
        unsigned u[4];
        #pragma unroll
        for (int wq = 0; wq < 4; ++wq) {
          int k0 = 32*kt + 8*g + 2*wq;
          u[wq] = pk2(W2g[k0*64 + mpsi[mt]], W2g[(k0+1)*64 + mpsi[mt]]);
        }
        w2f[kt][mt] = mkfrag(u[0], u[1], u[2], u[3]);
      }
    // ---- W3 A-frags (M=12 padded to 16 with zeros) ----
    bf16x8 w3f[2];
    #pragma unroll
    for (int kt = 0; kt < 2; ++kt) {
      unsigned u[4];
      #pragma unroll
      for (int wq = 0; wq < 4; ++wq) {
        int k0 = 32*kt + 8*g + 2*wq;
        float v0 = (q < 12) ? W3g[k0*12 + q]     : 0.f;
        float v1 = (q < 12) ? W3g[(k0+1)*12 + q] : 0.f;
        u[wq] = pk2(v0, v1);
      }
      w3f[kt] = mkfrag(u[0], u[1], u[2], u[3]);
    }
    // ---- biases as C-init: C row = 4g+reg ----
    f32x4 b2f[4], b3f;
    #pragma unroll
    for (int mt = 0; mt < 4; ++mt) {
      #pragma unroll
      for (int r = 0; r < 4; ++r)
        b2f[mt][r] = b2g[32*(mt>>1) + 8*g + 4*(mt&1) + r];   // b2[psi(16mt+4g+r)]
    }
    #pragma unroll
    for (int r = 0; r < 4; ++r) {
      int m = 4*g + r;
      b3f[r] = (m < 12) ? b3g[m] : 0.f;
    }

    // ---------------- main: 8 chunks of 16 rows; unroll 2 (r11-verified) ----------------
    #pragma unroll 2
    for (int ch = 0; ch < 8; ++ch) {
      const int row = ch * 16 + q;
      bf16x8 xb = *(const bf16x8*)(xs + (p * RT + row) * XSTR + 8 * g);

      f32x4 c1[4];
      #pragma unroll
      for (int mt = 0; mt < 4; ++mt) c1[mt] = mfma16(w1f[mt], xb, f32x4{0.f,0.f,0.f,0.f});

      // hop1 (truncating pack — activations only)
      bf16x8 fr1[2];
      #pragma unroll
      for (int kt = 0; kt < 2; ++kt)
        fr1[kt] = mkfrag(
          pk2t(fmaxf(c1[2*kt][0], 0.f),   fmaxf(c1[2*kt][1], 0.f)),
          pk2t(fmaxf(c1[2*kt][2], 0.f),   fmaxf(c1[2*kt][3], 0.f)),
          pk2t(fmaxf(c1[2*kt+1][0], 0.f), fmaxf(c1[2*kt+1][1], 0.f)),
          pk2t(fmaxf(c1[2*kt+1][2], 0.f), fmaxf(c1[2*kt+1][3], 0.f)));

      f32x4 c2[4];
      #pragma unroll
      for (int mt = 0; mt < 4; ++mt) {
        c2[mt] = mfma16(w2f[0][mt], fr1[0], b2f[mt]);
        c2[mt] = mfma16(w2f[1][mt], fr1[1], c2[mt]);
      }
      // hop2 (truncating pack)
      bf16x8 fr2[2];
      #pragma unroll
      for (int kt = 0; kt < 2; ++kt)
        fr2[kt] = mkfrag(
          pk2t(fmaxf(c2[2*kt][0], 0.f),   fmaxf(c2[2*kt][1], 0.f)),
          pk2t(fmaxf(c2[2*kt][2], 0.f),   fmaxf(c2[2*kt][3], 0.f)),
          pk2t(fmaxf(c2[2*kt+1][0], 0.f), fmaxf(c2[2*kt+1][1], 0.f)),
          pk2t(fmaxf(c2[2*kt+1][2], 0.f), fmaxf(c2[2*kt+1][3], 0.f)));

      f32x4 c3 = mfma16(w3f[0], fr2[0], b3f);
      c3 = mfma16(w3f[1], fr2[1], c3);

      // o-write: direct f32x4 store (no pack); C reg r = out-feat 4g+r
      if (g < 3)
        *(f32x4*)(os + ((p * 2 + c) * 129 + row) * 12 + 4 * g) = c3;
    }
    __syncthreads();

    // ---------------- residual combine (o now f32: no unp4 on o paths) ----------------
    {
      const int r = tid >> 2, pp = tid & 3;
      float sum[24], own[24], yn[24];
      #pragma unroll
      for (int k = 0; k < 24; ++k) sum[k] = 0.f;
      #pragma unroll
      for (int pp2 = 0; pp2 < 4; ++pp2)
        #pragma unroll
        for (int cc2 = 0; cc2 < 2; ++cc2) {
          const f32x4* orow = (const f32x4*)(os + ((pp2 * 2 + cc2) * 129 + r) * 12);
          #pragma unroll
          for (int i = 0; i < 3; ++i) {
            f32x4 t = orow[i];
            sum[cc2*12 + 4*i + 0] += t[0];
            sum[cc2*12 + 4*i + 1] += t[1];
            sum[cc2*12 + 4*i + 2] += t[2];
            sum[cc2*12 + 4*i + 3] += t[3];
          }
        }
      #pragma unroll
      for (int cc2 = 0; cc2 < 2; ++cc2) {
        const f32x4* orow = (const f32x4*)(os + ((pp * 2 + cc2) * 129 + r) * 12);
        #pragma unroll
        for (int i = 0; i < 3; ++i) {
          f32x4 t = orow[i];
          own[cc2*12 + 4*i + 0] = t[0];
          own[cc2*12 + 4*i + 1] = t[1];
          own[cc2*12 + 4*i + 2] = t[2];
          own[cc2*12 + 4*i + 3] = t[3];
        }
        const ull* yrow = (const ull*)(ys + (cc2 * RT + r) * 12);
        unp4(yrow[0], yn + cc2 * 12); unp4(yrow[1], yn + cc2 * 12 + 4); unp4(yrow[2], yn + cc2 * 12 + 8);
      }
      if (s < 2) {
        unsigned xw[12];
        #pragma unroll
        for (int j = 0; j < 12; ++j) {
          float v0 = own[2*j]   + (yn[2*j]   - sum[2*j]);
          float v1 = own[2*j+1] + (yn[2*j+1] - sum[2*j+1]);
          xw[j] = pk2(v0, v1);
        }
        u32x4* xr = (u32x4*)(xs + (pp * RT + r) * XSTR);
        u32x4 t0; t0[0]=xw[0]; t0[1]=xw[1]; t0[2]=xw[2];  t0[3]=xw[3];
        u32x4 t1; t1[0]=xw[4]; t1[1]=xw[5]; t1[2]=xw[6];  t1[3]=xw[7];
        u32x4 t2; t2[0]=xw[8]; t2[1]=xw[9]; t2[2]=xw[10]; t2[3]=xw[11];
        xr[0]=t0; xr[1]=t1; xr[2]=t2;
        __syncthreads();
      } else {
        const float ev = es[r];
        float vals[24];
        #pragma unroll
        for (int l = 0; l < 12; ++l) {
          vals[2*l]   = (own[l]      + yn[l]      - sum[l])      * ev;
          vals[2*l+1] = (own[12 + l] + yn[12 + l] - sum[12 + l]) * ev;
        }
        __syncthreads();                       // all o/y/e reads done
        float* vstg = (float*)smem;            // overlays x + front of o (reads complete)
        f32x4* vw = (f32x4*)(vstg + r * 96 + pp * 24);
        #pragma unroll
        for (int i = 0; i < 6; ++i) {
          f32x4 t; t[0]=vals[4*i]; t[1]=vals[4*i+1]; t[2]=vals[4*i+2]; t[3]=vals[4*i+3];
          vw[i] = t;
        }
        __syncthreads();
        const f32x4* vp = (const f32x4*)vstg;
        f32x4* og = (f32x4*)(out + r0 * 96);
        #pragma unroll
        for (int i = 0; i < 6; ++i) og[tid + 512 * i] = vp[tid + 512 * i];
      }
    }
  }
}

extern "C" void kernel_launch(void* const* d_in, const int* in_sizes, int n_in,
                              void* d_out, int out_size, void* d_ws, size_t ws_size,
                              hipStream_t stream) {
  const float* y_real = (const float*)d_in[0];
  const float* y_imag = (const float*)d_in[1];
  const float* W1 = (const float*)d_in[2];
  const float* b1 = (const float*)d_in[3];
  const float* W2 = (const float*)d_in[4];
  const float* b2 = (const float*)d_in[5];
  const float* W3 = (const float*)d_in[6];
  const float* b3 = (const float*)d_in[7];
  float* out = (float*)d_out;

  hipLaunchKernelGGL(rrsep, dim3(NB), dim3(512), 0, stream,
                     y_real, y_imag, W1, b1, W2, b2, W3, b3, out);
}

// Round 18
// 176.452 us; speedup vs baseline: 1.6987x; 1.6112x over previous
//
#include <hip/hip_runtime.h>
#include <hip/hip_bf16.h>

typedef __attribute__((ext_vector_type(8))) short bf16x8;
typedef __attribute__((ext_vector_type(4))) float f32x4;
typedef __attribute__((ext_vector_type(4))) unsigned int u32x4;
typedef unsigned long long ull;

#define RT 128
#define NB (262144 / RT)
#define XSTR 32
#define NFRAG 19   // 0-3 w1f, 4-11 w2f[kt*4+mt], 12-13 w3f, 14-17 b2f, 18 b3f

// LDS byte offsets — 95,104 B (1 block/CU; residency register-locked, r15/r16)
#define X_OFF 0          // x: [4][128][32] bf16    = 32768 B
#define O_OFF 32768      // o: [4][2][129][12] f32  = 49536 B
#define Y_OFF 82304      // y: [2][128][12] f32     = 12288 B   (ROUND-18: was bf16)
#define E_OFF 94592      // e: [128] f32            =   512 B
#define SMEM_BYTES 95104

// RNE 3-VALU pack (r6-verified) — weights / state / prologue.
__device__ __forceinline__ unsigned pk2(float lo, float hi) {
  union { float f; unsigned u; } a, b;
  a.f = lo; b.f = hi;
  return __builtin_amdgcn_perm(b.u + 0x8000u, a.u + 0x8000u, 0x07060302u);
}
// truncating 1-VALU pack for inter-layer activations (r17-verified, absmax 0.1875)
__device__ __forceinline__ unsigned pk2t(float lo, float hi) {
  union { float f; unsigned u; } a, b;
  a.f = lo; b.f = hi;
  return __builtin_amdgcn_perm(b.u, a.u, 0x07060302u);
}
__device__ __forceinline__ bf16x8 mkfrag(unsigned w0, unsigned w1, unsigned w2, unsigned w3) {
  union { bf16x8 v; unsigned u[4]; } U;
  U.u[0] = w0; U.u[1] = w1; U.u[2] = w2; U.u[3] = w3;
  return U.v;
}
__device__ __forceinline__ f32x4 mfma16(bf16x8 a, bf16x8 b, f32x4 c) {
  return __builtin_amdgcn_mfma_f32_16x16x32_bf16(a, b, c, 0, 0, 0);
}

// ================= ROUND-18 prep kernel: pack weight fragments once =================
// Grid 24 (pc) x 64 (lane). Writes [pc][frag][lane] u32x4 to ws — main kernel
// then loads each fragment as ONE coalesced dwordx4 instead of rebuilding from
// ~112 scalar loads + ~170 VALU per lane per stage per block (r17 cost).
__global__ void wpack(const float* __restrict__ W1, const float* __restrict__ b1,
                      const float* __restrict__ W2, const float* __restrict__ b2,
                      const float* __restrict__ W3, const float* __restrict__ b3,
                      u32x4* __restrict__ ws)
{
  const int pc = blockIdx.x;       // 0..23 = (s*4+p)*2+c
  const int lane = threadIdx.x;    // 0..63
  const int q = lane & 15, g = lane >> 4;
  int mpsi[4];
  #pragma unroll
  for (int mt = 0; mt < 4; ++mt)
    mpsi[mt] = 32*(mt>>1) + 8*(q>>2) + 4*(mt&1) + (q&3);

  const float* W1g = W1 + pc * 24 * 64;
  const float* b1g = b1 + pc * 64;
  const float* W2g = W2 + pc * 64 * 64;
  const float* b2g = b2 + pc * 64;
  const float* W3g = W3 + pc * 64 * 12;
  const float* b3g = b3 + pc * 12;
  u32x4* dst = ws + pc * NFRAG * 64 + lane;   // frag f at dst[f*64]

  // w1f (psi on output cols, b1 folded at k=24)
  #pragma unroll
  for (int mt = 0; mt < 4; ++mt) {
    unsigned u[4];
    #pragma unroll
    for (int wq = 0; wq < 4; ++wq) {
      int k0 = 8*g + 2*wq;
      float v0 = (k0 < 24) ? W1g[k0*64 + mpsi[mt]] : ((k0 == 24) ? b1g[mpsi[mt]] : 0.f);
      float v1 = (k0+1 < 24) ? W1g[(k0+1)*64 + mpsi[mt]] : 0.f;
      u[wq] = pk2(v0, v1);
    }
    u32x4 t; t[0]=u[0]; t[1]=u[1]; t[2]=u[2]; t[3]=u[3];
    dst[mt * 64] = t;
  }
  // w2f (input k actual, psi on output cols)
  #pragma unroll
  for (int kt = 0; kt < 2; ++kt)
    #pragma unroll
    for (int mt = 0; mt < 4; ++mt) {
      unsigned u[4];
      #pragma unroll
      for (int wq = 0; wq < 4; ++wq) {
        int k0 = 32*kt + 8*g + 2*wq;
        u[wq] = pk2(W2g[k0*64 + mpsi[mt]], W2g[(k0+1)*64 + mpsi[mt]]);
      }
      u32x4 t; t[0]=u[0]; t[1]=u[1]; t[2]=u[2]; t[3]=u[3];
      dst[(4 + kt*4 + mt) * 64] = t;
    }
  // w3f (M=12 padded to 16 with zeros)
  #pragma unroll
  for (int kt = 0; kt < 2; ++kt) {
    unsigned u[4];
    #pragma unroll
    for (int wq = 0; wq < 4; ++wq) {
      int k0 = 32*kt + 8*g + 2*wq;
      float v0 = (q < 12) ? W3g[k0*12 + q]     : 0.f;
      float v1 = (q < 12) ? W3g[(k0+1)*12 + q] : 0.f;
      u[wq] = pk2(v0, v1);
    }
    u32x4 t; t[0]=u[0]; t[1]=u[1]; t[2]=u[2]; t[3]=u[3];
    dst[(12 + kt) * 64] = t;
  }
  // b2f (f32x4 raw): b2[psi(16mt+4g+r)]
  #pragma unroll
  for (int mt = 0; mt < 4; ++mt) {
    f32x4 bv;
    #pragma unroll
    for (int r = 0; r < 4; ++r) bv[r] = b2g[32*(mt>>1) + 8*g + 4*(mt&1) + r];
    union { f32x4 f; u32x4 u; } U; U.f = bv;
    dst[(14 + mt) * 64] = U.u;
  }
  // b3f
  {
    f32x4 bv;
    #pragma unroll
    for (int r = 0; r < 4; ++r) {
      int m = 4*g + r;
      bv[r] = (m < 12) ? b3g[m] : 0.f;
    }
    union { f32x4 f; u32x4 u; } U; U.f = bv;
    dst[18 * 64] = U.u;
  }
}

// ================= main kernel (r17 base minus in-kernel weight pack) =================
// psi-16x16 (r8-verified), unroll-2 chunks (r11), f32 o_lds + pk2t hops (r17).
__global__ __launch_bounds__(512, 2) void rrsep(
    const float* __restrict__ y_real, const float* __restrict__ y_imag,
    const u32x4* __restrict__ wsf, float* __restrict__ out)
{
  __shared__ __align__(16) char smem[SMEM_BYTES];
  unsigned short* xs = (unsigned short*)(smem + X_OFF);
  float*          os = (float*)(smem + O_OFF);
  float*          ysf = (float*)(smem + Y_OFF);
  float*          es = (float*)(smem + E_OFF);

  const int tid  = (int)threadIdx.x;
  const int lane = tid & 63;
  const int w    = tid >> 6;     // wave 0..7
  const int p    = w >> 1;       // port
  const int c    = w & 1;        // channel
  const int q    = lane & 15;
  const int g    = lane >> 4;
  const long r0  = (long)blockIdx.x * RT;

  // ---------------- prologue: coalesced load, normalize, init x ----------------
  {
    float* stg = (float*)smem;   // overlays x region before its first use
    if (tid < 384) {
      ((f32x4*)stg)[tid]          = ((const f32x4*)(y_real + r0 * 12))[tid];
      ((f32x4*)(stg + 1536))[tid] = ((const f32x4*)(y_imag + r0 * 12))[tid];
    }
    __syncthreads();
    float yv[24]; float ev = 0.f, inv = 0.f;
    if (tid < RT) {
      float acc = 0.f;
      #pragma unroll
      for (int l = 0; l < 12; ++l) {
        yv[l]      = stg[tid * 12 + l];
        yv[12 + l] = stg[1536 + tid * 12 + l];
        acc += yv[l] * yv[l] + yv[12 + l] * yv[12 + l];
      }
      ev  = sqrtf(acc * (1.f / 12.f));
      inv = 1.f / (ev + 1e-8f);
    }
    __syncthreads();   // all slab reads done before x/y overwrite the region
    if (tid < RT) {
      es[tid] = ev;
      // y normalized, stored f32 (ROUND-18: kills unp4 in combine, improves accuracy)
      #pragma unroll
      for (int i = 0; i < 6; ++i) {
        f32x4 t;
        t[0] = yv[4*i+0] * inv; t[1] = yv[4*i+1] * inv;
        t[2] = yv[4*i+2] * inv; t[3] = yv[4*i+3] * inv;
        int l0 = 4*i;                       // feats l0..l0+3; first 12 real, next 12 imag
        float* yr = ysf + ((l0 < 12) ? (0 * RT + tid) * 12 + l0 : (1 * RT + tid) * 12 + (l0 - 12));
        *(f32x4*)yr = t;
      }
      unsigned pkw[12];
      #pragma unroll
      for (int j = 0; j < 12; ++j) pkw[j] = pk2(yv[2*j] * inv, yv[2*j+1] * inv);
      #pragma unroll
      for (int p2 = 0; p2 < 4; ++p2) {
        u32x4* xr = (u32x4*)(xs + (p2 * RT + tid) * XSTR);
        u32x4 t0; t0[0]=pkw[0]; t0[1]=pkw[1]; t0[2]=pkw[2]; t0[3]=pkw[3];
        u32x4 t1; t1[0]=pkw[4]; t1[1]=pkw[5]; t1[2]=pkw[6]; t1[3]=pkw[7];
        u32x4 t2; t2[0]=pkw[8]; t2[1]=pkw[9]; t2[2]=pkw[10]; t2[3]=pkw[11];
        u32x4 t3; t3[0]=pk2(1.f, 0.f); t3[1]=0u; t3[2]=0u; t3[3]=0u;  // aug x[24]=1
        xr[0]=t0; xr[1]=t1; xr[2]=t2; xr[3]=t3;
      }
    }
    __syncthreads();
  }

  #pragma unroll 1
  for (int s = 0; s < 3; ++s) {
    const int pc = (s * 4 + p) * 2 + c;
    const u32x4* wb = wsf + pc * NFRAG * 64 + lane;   // frag f at wb[f*64], coalesced

    bf16x8 w1f[4], w2f[2][4], w3f[2];
    f32x4 b2f[4], b3f;
    #pragma unroll
    for (int mt = 0; mt < 4; ++mt) {
      union { u32x4 u; bf16x8 v; } U; U.u = wb[mt * 64];
      w1f[mt] = U.v;
    }
    #pragma unroll
    for (int kt = 0; kt < 2; ++kt)
      #pragma unroll
      for (int mt = 0; mt < 4; ++mt) {
        union { u32x4 u; bf16x8 v; } U; U.u = wb[(4 + kt*4 + mt) * 64];
        w2f[kt][mt] = U.v;
      }
    #pragma unroll
    for (int kt = 0; kt < 2; ++kt) {
      union { u32x4 u; bf16x8 v; } U; U.u = wb[(12 + kt) * 64];
      w3f[kt] = U.v;
    }
    #pragma unroll
    for (int mt = 0; mt < 4; ++mt) {
      union { u32x4 u; f32x4 f; } U; U.u = wb[(14 + mt) * 64];
      b2f[mt] = U.f;
    }
    {
      union { u32x4 u; f32x4 f; } U; U.u = wb[18 * 64];
      b3f = U.f;
    }

    // ---------------- main: 8 chunks of 16 rows; unroll 2 (r11-verified) ----------------
    #pragma unroll 2
    for (int ch = 0; ch < 8; ++ch) {
      const int row = ch * 16 + q;
      bf16x8 xb = *(const bf16x8*)(xs + (p * RT + row) * XSTR + 8 * g);

      f32x4 c1[4];
      #pragma unroll
      for (int mt = 0; mt < 4; ++mt) c1[mt] = mfma16(w1f[mt], xb, f32x4{0.f,0.f,0.f,0.f});

      bf16x8 fr1[2];
      #pragma unroll
      for (int kt = 0; kt < 2; ++kt)
        fr1[kt] = mkfrag(
          pk2t(fmaxf(c1[2*kt][0], 0.f),   fmaxf(c1[2*kt][1], 0.f)),
          pk2t(fmaxf(c1[2*kt][2], 0.f),   fmaxf(c1[2*kt][3], 0.f)),
          pk2t(fmaxf(c1[2*kt+1][0], 0.f), fmaxf(c1[2*kt+1][1], 0.f)),
          pk2t(fmaxf(c1[2*kt+1][2], 0.f), fmaxf(c1[2*kt+1][3], 0.f)));

      f32x4 c2[4];
      #pragma unroll
      for (int mt = 0; mt < 4; ++mt) {
        c2[mt] = mfma16(w2f[0][mt], fr1[0], b2f[mt]);
        c2[mt] = mfma16(w2f[1][mt], fr1[1], c2[mt]);
      }
      bf16x8 fr2[2];
      #pragma unroll
      for (int kt = 0; kt < 2; ++kt)
        fr2[kt] = mkfrag(
          pk2t(fmaxf(c2[2*kt][0], 0.f),   fmaxf(c2[2*kt][1], 0.f)),
          pk2t(fmaxf(c2[2*kt][2], 0.f),   fmaxf(c2[2*kt][3], 0.f)),
          pk2t(fmaxf(c2[2*kt+1][0], 0.f), fmaxf(c2[2*kt+1][1], 0.f)),
          pk2t(fmaxf(c2[2*kt+1][2], 0.f), fmaxf(c2[2*kt+1][3], 0.f)));

      f32x4 c3 = mfma16(w3f[0], fr2[0], b3f);
      c3 = mfma16(w3f[1], fr2[1], c3);

      if (g < 3)
        *(f32x4*)(os + ((p * 2 + c) * 129 + row) * 12 + 4 * g) = c3;
    }
    __syncthreads();

    // ---------------- residual combine (o f32, y f32) ----------------
    {
      const int r = tid >> 2, pp = tid & 3;
      float sum[24], own[24], yn[24];
      #pragma unroll
      for (int k = 0; k < 24; ++k) sum[k] = 0.f;
      #pragma unroll
      for (int pp2 = 0; pp2 < 4; ++pp2)
        #pragma unroll
        for (int cc2 = 0; cc2 < 2; ++cc2) {
          const f32x4* orow = (const f32x4*)(os + ((pp2 * 2 + cc2) * 129 + r) * 12);
          #pragma unroll
          for (int i = 0; i < 3; ++i) {
            f32x4 t = orow[i];
            sum[cc2*12 + 4*i + 0] += t[0];
            sum[cc2*12 + 4*i + 1] += t[1];
            sum[cc2*12 + 4*i + 2] += t[2];
            sum[cc2*12 + 4*i + 3] += t[3];
          }
        }
      #pragma unroll
      for (int cc2 = 0; cc2 < 2; ++cc2) {
        const f32x4* orow = (const f32x4*)(os + ((pp * 2 + cc2) * 129 + r) * 12);
        const f32x4* yrow = (const f32x4*)(ysf + (cc2 * RT + r) * 12);
        #pragma unroll
        for (int i = 0; i < 3; ++i) {
          f32x4 t = orow[i], u = yrow[i];
          own[cc2*12 + 4*i + 0] = t[0]; yn[cc2*12 + 4*i + 0] = u[0];
          own[cc2*12 + 4*i + 1] = t[1]; yn[cc2*12 + 4*i + 1] = u[1];
          own[cc2*12 + 4*i + 2] = t[2]; yn[cc2*12 + 4*i + 2] = u[2];
          own[cc2*12 + 4*i + 3] = t[3]; yn[cc2*12 + 4*i + 3] = u[3];
        }
      }
      if (s < 2) {
        unsigned xw[12];
        #pragma unroll
        for (int j = 0; j < 12; ++j) {
          float v0 = own[2*j]   + (yn[2*j]   - sum[2*j]);
          float v1 = own[2*j+1] + (yn[2*j+1] - sum[2*j+1]);
          xw[j] = pk2(v0, v1);
        }
        u32x4* xr = (u32x4*)(xs + (pp * RT + r) * XSTR);
        u32x4 t0; t0[0]=xw[0]; t0[1]=xw[1]; t0[2]=xw[2];  t0[3]=xw[3];
        u32x4 t1; t1[0]=xw[4]; t1[1]=xw[5]; t1[2]=xw[6];  t1[3]=xw[7];
        u32x4 t2; t2[0]=xw[8]; t2[1]=xw[9]; t2[2]=xw[10]; t2[3]=xw[11];
        xr[0]=t0; xr[1]=t1; xr[2]=t2;
        __syncthreads();
      } else {
        const float ev = es[r];
        float vals[24];
        #pragma unroll
        for (int l = 0; l < 12; ++l) {
          vals[2*l]   = (own[l]      + yn[l]      - sum[l])      * ev;
          vals[2*l+1] = (own[12 + l] + yn[12 + l] - sum[12 + l]) * ev;
        }
        __syncthreads();                       // all o/y/e reads done
        float* vstg = (float*)smem;            // overlays x + front of o (reads complete)
        f32x4* vw = (f32x4*)(vstg + r * 96 + pp * 24);
        #pragma unroll
        for (int i = 0; i < 6; ++i) {
          f32x4 t; t[0]=vals[4*i]; t[1]=vals[4*i+1]; t[2]=vals[4*i+2]; t[3]=vals[4*i+3];
          vw[i] = t;
        }
        __syncthreads();
        const f32x4* vp = (const f32x4*)vstg;
        f32x4* og = (f32x4*)(out + r0 * 96);
        #pragma unroll
        for (int i = 0; i < 6; ++i) og[tid + 512 * i] = vp[tid + 512 * i];
      }
    }
  }
}

extern "C" void kernel_launch(void* const* d_in, const int* in_sizes, int n_in,
                              void* d_out, int out_size, void* d_ws, size_t ws_size,
                              hipStream_t stream) {
  const float* y_real = (const float*)d_in[0];
  const float* y_imag = (const float*)d_in[1];
  const float* W1 = (const float*)d_in[2];
  const float* b1 = (const float*)d_in[3];
  const float* W2 = (const float*)d_in[4];
  const float* b2 = (const float*)d_in[5];
  const float* W3 = (const float*)d_in[6];
  const float* b3 = (const float*)d_in[7];
  float* out = (float*)d_out;
  u32x4* ws = (u32x4*)d_ws;   // needs 24*19*64*16 = 466,944 B

  hipLaunchKernelGGL(wpack, dim3(24), dim3(64), 0, stream,
                     W1, b1, W2, b2, W3, b3, ws);
  hipLaunchKernelGGL(rrsep, dim3(NB), dim3(512), 0, stream,
                     y_real, y_imag, ws, out);
}

// Round 19
// 147.838 us; speedup vs baseline: 2.0275x; 1.1936x over previous
//
#include <hip/hip_runtime.h>
#include <hip/hip_bf16.h>

typedef __attribute__((ext_vector_type(8))) short bf16x8;
typedef __attribute__((ext_vector_type(4))) float f32x4;
typedef __attribute__((ext_vector_type(4))) unsigned int u32x4;
typedef unsigned long long ull;

#define RT 64
#define NB (262144 / RT)
#define XSTR 32
#define NFRAG 19   // 0-3 w1f, 4-11 w2f[kt*4+mt], 12-13 w3f, 14-17 b2f, 18 b3f

// LDS byte offsets — 47,744 B/block -> 3 blocks/CU (143.2KB <= 160KB)
#define X_OFF 0          // x: [4][64][32] bf16    = 16384 B
#define O_OFF 16384      // o: [4][2][65][12] f32  = 24960 B
#define Y_OFF 41344      // y: [2][64][12] f32     =  6144 B
#define E_OFF 47488      // e: [64] f32            =   256 B
#define SMEM_BYTES 47744

// RNE 3-VALU pack (r6-verified) — weights / state / prologue.
__device__ __forceinline__ unsigned pk2(float lo, float hi) {
  union { float f; unsigned u; } a, b;
  a.f = lo; b.f = hi;
  return __builtin_amdgcn_perm(b.u + 0x8000u, a.u + 0x8000u, 0x07060302u);
}
// truncating 1-VALU pack for inter-layer activations (r17-verified)
__device__ __forceinline__ unsigned pk2t(float lo, float hi) {
  union { float f; unsigned u; } a, b;
  a.f = lo; b.f = hi;
  return __builtin_amdgcn_perm(b.u, a.u, 0x07060302u);
}
__device__ __forceinline__ bf16x8 mkfrag(unsigned w0, unsigned w1, unsigned w2, unsigned w3) {
  union { bf16x8 v; unsigned u[4]; } U;
  U.u[0] = w0; U.u[1] = w1; U.u[2] = w2; U.u[3] = w3;
  return U.v;
}
__device__ __forceinline__ f32x4 mfma16(bf16x8 a, bf16x8 b, f32x4 c) {
  return __builtin_amdgcn_mfma_f32_16x16x32_bf16(a, b, c, 0, 0, 0);
}

// ================= prep kernel: pack weight fragments once (r18-verified) =================
__global__ void wpack(const float* __restrict__ W1, const float* __restrict__ b1,
                      const float* __restrict__ W2, const float* __restrict__ b2,
                      const float* __restrict__ W3, const float* __restrict__ b3,
                      u32x4* __restrict__ ws)
{
  const int pc = blockIdx.x;       // 0..23 = (s*4+p)*2+c
  const int lane = threadIdx.x;    // 0..63
  const int q = lane & 15, g = lane >> 4;
  int mpsi[4];
  #pragma unroll
  for (int mt = 0; mt < 4; ++mt)
    mpsi[mt] = 32*(mt>>1) + 8*(q>>2) + 4*(mt&1) + (q&3);

  const float* W1g = W1 + pc * 24 * 64;
  const float* b1g = b1 + pc * 64;
  const float* W2g = W2 + pc * 64 * 64;
  const float* b2g = b2 + pc * 64;
  const float* W3g = W3 + pc * 64 * 12;
  const float* b3g = b3 + pc * 12;
  u32x4* dst = ws + pc * NFRAG * 64 + lane;   // frag f at dst[f*64]

  #pragma unroll
  for (int mt = 0; mt < 4; ++mt) {
    unsigned u[4];
    #pragma unroll
    for (int wq = 0; wq < 4; ++wq) {
      int k0 = 8*g + 2*wq;
      float v0 = (k0 < 24) ? W1g[k0*64 + mpsi[mt]] : ((k0 == 24) ? b1g[mpsi[mt]] : 0.f);
      float v1 = (k0+1 < 24) ? W1g[(k0+1)*64 + mpsi[mt]] : 0.f;
      u[wq] = pk2(v0, v1);
    }
    u32x4 t; t[0]=u[0]; t[1]=u[1]; t[2]=u[2]; t[3]=u[3];
    dst[mt * 64] = t;
  }
  #pragma unroll
  for (int kt = 0; kt < 2; ++kt)
    #pragma unroll
    for (int mt = 0; mt < 4; ++mt) {
      unsigned u[4];
      #pragma unroll
      for (int wq = 0; wq < 4; ++wq) {
        int k0 = 32*kt + 8*g + 2*wq;
        u[wq] = pk2(W2g[k0*64 + mpsi[mt]], W2g[(k0+1)*64 + mpsi[mt]]);
      }
      u32x4 t; t[0]=u[0]; t[1]=u[1]; t[2]=u[2]; t[3]=u[3];
      dst[(4 + kt*4 + mt) * 64] = t;
    }
  #pragma unroll
  for (int kt = 0; kt < 2; ++kt) {
    unsigned u[4];
    #pragma unroll
    for (int wq = 0; wq < 4; ++wq) {
      int k0 = 32*kt + 8*g + 2*wq;
      float v0 = (q < 12) ? W3g[k0*12 + q]     : 0.f;
      float v1 = (q < 12) ? W3g[(k0+1)*12 + q] : 0.f;
      u[wq] = pk2(v0, v1);
    }
    u32x4 t; t[0]=u[0]; t[1]=u[1]; t[2]=u[2]; t[3]=u[3];
    dst[(12 + kt) * 64] = t;
  }
  #pragma unroll
  for (int mt = 0; mt < 4; ++mt) {
    f32x4 bv;
    #pragma unroll
    for (int r = 0; r < 4; ++r) bv[r] = b2g[32*(mt>>1) + 8*g + 4*(mt&1) + r];
    union { f32x4 f; u32x4 u; } U; U.f = bv;
    dst[(14 + mt) * 64] = U.u;
  }
  {
    f32x4 bv;
    #pragma unroll
    for (int r = 0; r < 4; ++r) {
      int m = 4*g + r;
      bv[r] = (m < 12) ? b3g[m] : 0.f;
    }
    union { f32x4 f; u32x4 u; } U; U.f = bv;
    dst[18 * 64] = U.u;
  }
}

// ================= ROUND-19 main: RT=64, 256-thread blocks, 3 blocks/CU =================
// r18: 184us prof; reg demand collapsed (VGPR 88) -> residency now LDS-limited
// (95KB > 80KB). RT=64 + 256 threads (wave=port, cc sequential per r16; cheap
// now since weights are pre-packed: 19 coalesced dwordx4 per cc) cuts LDS to
// 47.7KB -> 3 blocks/CU at launch_bounds(256,3) (170-reg budget, no spill
// risk). Same per-SIMD lifetime work, 3 resident waves/SIMD instead of 2 to
// hide the ~60us stall. psi-16x16 (r8), unroll-2 (r11), f32 o/y (r17/r18).
__global__ __launch_bounds__(256, 3) void rrsep(
    const float* __restrict__ y_real, const float* __restrict__ y_imag,
    const u32x4* __restrict__ wsf, float* __restrict__ out)
{
  __shared__ __align__(16) char smem[SMEM_BYTES];
  unsigned short* xs = (unsigned short*)(smem + X_OFF);
  float*          os = (float*)(smem + O_OFF);
  float*          ysf = (float*)(smem + Y_OFF);
  float*          es = (float*)(smem + E_OFF);

  const int tid  = (int)threadIdx.x;
  const int lane = tid & 63;
  const int p    = tid >> 6;     // wave 0..3 = port
  const int q    = lane & 15;
  const int g    = lane >> 4;
  const long r0  = (long)blockIdx.x * RT;

  // ---------------- prologue: coalesced load, normalize, init x ----------------
  {
    float* stg = (float*)smem;   // overlays x region before its first use
    if (tid < 192) {             // 64 rows x 12 = 768 f32 = 192 f32x4 per component
      ((f32x4*)stg)[tid]         = ((const f32x4*)(y_real + r0 * 12))[tid];
      ((f32x4*)(stg + 768))[tid] = ((const f32x4*)(y_imag + r0 * 12))[tid];
    }
    __syncthreads();
    float yv[24]; float ev = 0.f, inv = 0.f;
    if (tid < RT) {
      float acc = 0.f;
      #pragma unroll
      for (int l = 0; l < 12; ++l) {
        yv[l]      = stg[tid * 12 + l];
        yv[12 + l] = stg[768 + tid * 12 + l];
        acc += yv[l] * yv[l] + yv[12 + l] * yv[12 + l];
      }
      ev  = sqrtf(acc * (1.f / 12.f));
      inv = 1.f / (ev + 1e-8f);
    }
    __syncthreads();   // all slab reads done before x/y overwrite the region
    if (tid < RT) {
      es[tid] = ev;
      // y normalized, f32 (r18)
      #pragma unroll
      for (int i = 0; i < 6; ++i) {
        f32x4 t;
        t[0] = yv[4*i+0] * inv; t[1] = yv[4*i+1] * inv;
        t[2] = yv[4*i+2] * inv; t[3] = yv[4*i+3] * inv;
        int l0 = 4*i;
        float* yr = ysf + ((l0 < 12) ? (0 * RT + tid) * 12 + l0 : (1 * RT + tid) * 12 + (l0 - 12));
        *(f32x4*)yr = t;
      }
      unsigned pkw[12];
      #pragma unroll
      for (int j = 0; j < 12; ++j) pkw[j] = pk2(yv[2*j] * inv, yv[2*j+1] * inv);
      #pragma unroll
      for (int p2 = 0; p2 < 4; ++p2) {
        u32x4* xr = (u32x4*)(xs + (p2 * RT + tid) * XSTR);
        u32x4 t0; t0[0]=pkw[0]; t0[1]=pkw[1]; t0[2]=pkw[2]; t0[3]=pkw[3];
        u32x4 t1; t1[0]=pkw[4]; t1[1]=pkw[5]; t1[2]=pkw[6]; t1[3]=pkw[7];
        u32x4 t2; t2[0]=pkw[8]; t2[1]=pkw[9]; t2[2]=pkw[10]; t2[3]=pkw[11];
        u32x4 t3; t3[0]=pk2(1.f, 0.f); t3[1]=0u; t3[2]=0u; t3[3]=0u;  // aug x[24]=1
        xr[0]=t0; xr[1]=t1; xr[2]=t2; xr[3]=t3;
      }
    }
    __syncthreads();
  }

  #pragma unroll 1
  for (int s = 0; s < 3; ++s) {
    // ---------- channel-sequential (r16); weights pre-packed (r18) ----------
    #pragma unroll 1
    for (int cc = 0; cc < 2; ++cc) {
      const int pc = (s * 4 + p) * 2 + cc;
      const u32x4* wb = wsf + pc * NFRAG * 64 + lane;   // frag f at wb[f*64]

      bf16x8 w1f[4], w2f[2][4], w3f[2];
      f32x4 b2f[4], b3f;
      #pragma unroll
      for (int mt = 0; mt < 4; ++mt) {
        union { u32x4 u; bf16x8 v; } U; U.u = wb[mt * 64];
        w1f[mt] = U.v;
      }
      #pragma unroll
      for (int kt = 0; kt < 2; ++kt)
        #pragma unroll
        for (int mt = 0; mt < 4; ++mt) {
          union { u32x4 u; bf16x8 v; } U; U.u = wb[(4 + kt*4 + mt) * 64];
          w2f[kt][mt] = U.v;
        }
      #pragma unroll
      for (int kt = 0; kt < 2; ++kt) {
        union { u32x4 u; bf16x8 v; } U; U.u = wb[(12 + kt) * 64];
        w3f[kt] = U.v;
      }
      #pragma unroll
      for (int mt = 0; mt < 4; ++mt) {
        union { u32x4 u; f32x4 f; } U; U.u = wb[(14 + mt) * 64];
        b2f[mt] = U.f;
      }
      {
        union { u32x4 u; f32x4 f; } U; U.u = wb[18 * 64];
        b3f = U.f;
      }

      // main: 4 chunks of 16 rows; unroll 2 (r11-verified)
      #pragma unroll 2
      for (int ch = 0; ch < RT / 16; ++ch) {
        const int row = ch * 16 + q;
        bf16x8 xb = *(const bf16x8*)(xs + (p * RT + row) * XSTR + 8 * g);

        f32x4 c1[4];
        #pragma unroll
        for (int mt = 0; mt < 4; ++mt) c1[mt] = mfma16(w1f[mt], xb, f32x4{0.f,0.f,0.f,0.f});

        bf16x8 fr1[2];
        #pragma unroll
        for (int kt = 0; kt < 2; ++kt)
          fr1[kt] = mkfrag(
            pk2t(fmaxf(c1[2*kt][0], 0.f),   fmaxf(c1[2*kt][1], 0.f)),
            pk2t(fmaxf(c1[2*kt][2], 0.f),   fmaxf(c1[2*kt][3], 0.f)),
            pk2t(fmaxf(c1[2*kt+1][0], 0.f), fmaxf(c1[2*kt+1][1], 0.f)),
            pk2t(fmaxf(c1[2*kt+1][2], 0.f), fmaxf(c1[2*kt+1][3], 0.f)));

        f32x4 c2[4];
        #pragma unroll
        for (int mt = 0; mt < 4; ++mt) {
          c2[mt] = mfma16(w2f[0][mt], fr1[0], b2f[mt]);
          c2[mt] = mfma16(w2f[1][mt], fr1[1], c2[mt]);
        }
        bf16x8 fr2[2];
        #pragma unroll
        for (int kt = 0; kt < 2; ++kt)
          fr2[kt] = mkfrag(
            pk2t(fmaxf(c2[2*kt][0], 0.f),   fmaxf(c2[2*kt][1], 0.f)),
            pk2t(fmaxf(c2[2*kt][2], 0.f),   fmaxf(c2[2*kt][3], 0.f)),
            pk2t(fmaxf(c2[2*kt+1][0], 0.f), fmaxf(c2[2*kt+1][1], 0.f)),
            pk2t(fmaxf(c2[2*kt+1][2], 0.f), fmaxf(c2[2*kt+1][3], 0.f)));

        f32x4 c3 = mfma16(w3f[0], fr2[0], b3f);
        c3 = mfma16(w3f[1], fr2[1], c3);

        if (g < 3)
          *(f32x4*)(os + ((p * 2 + cc) * 65 + row) * 12 + 4 * g) = c3;
      }
    }
    __syncthreads();

    // ------- residual combine: 256 (r,pp) units = 1/thread (o f32, y f32) -------
    {
      const int r = tid >> 2, pp = tid & 3;
      float sum[24], own[24], yn[24];
      #pragma unroll
      for (int k = 0; k < 24; ++k) sum[k] = 0.f;
      #pragma unroll
      for (int pp2 = 0; pp2 < 4; ++pp2)
        #pragma unroll
        for (int cc2 = 0; cc2 < 2; ++cc2) {
          const f32x4* orow = (const f32x4*)(os + ((pp2 * 2 + cc2) * 65 + r) * 12);
          #pragma unroll
          for (int i = 0; i < 3; ++i) {
            f32x4 t = orow[i];
            sum[cc2*12 + 4*i + 0] += t[0];
            sum[cc2*12 + 4*i + 1] += t[1];
            sum[cc2*12 + 4*i + 2] += t[2];
            sum[cc2*12 + 4*i + 3] += t[3];
          }
        }
      #pragma unroll
      for (int cc2 = 0; cc2 < 2; ++cc2) {
        const f32x4* orow = (const f32x4*)(os + ((pp * 2 + cc2) * 65 + r) * 12);
        const f32x4* yrow = (const f32x4*)(ysf + (cc2 * RT + r) * 12);
        #pragma unroll
        for (int i = 0; i < 3; ++i) {
          f32x4 t = orow[i], u = yrow[i];
          own[cc2*12 + 4*i + 0] = t[0]; yn[cc2*12 + 4*i + 0] = u[0];
          own[cc2*12 + 4*i + 1] = t[1]; yn[cc2*12 + 4*i + 1] = u[1];
          own[cc2*12 + 4*i + 2] = t[2]; yn[cc2*12 + 4*i + 2] = u[2];
          own[cc2*12 + 4*i + 3] = t[3]; yn[cc2*12 + 4*i + 3] = u[3];
        }
      }
      if (s < 2) {
        unsigned xw[12];
        #pragma unroll
        for (int j = 0; j < 12; ++j) {
          float v0 = own[2*j]   + (yn[2*j]   - sum[2*j]);
          float v1 = own[2*j+1] + (yn[2*j+1] - sum[2*j+1]);
          xw[j] = pk2(v0, v1);
        }
        u32x4* xr = (u32x4*)(xs + (pp * RT + r) * XSTR);
        u32x4 t0; t0[0]=xw[0]; t0[1]=xw[1]; t0[2]=xw[2];  t0[3]=xw[3];
        u32x4 t1; t1[0]=xw[4]; t1[1]=xw[5]; t1[2]=xw[6];  t1[3]=xw[7];
        u32x4 t2; t2[0]=xw[8]; t2[1]=xw[9]; t2[2]=xw[10]; t2[3]=xw[11];
        xr[0]=t0; xr[1]=t1; xr[2]=t2;
        __syncthreads();
      } else {
        const float ev = es[r];
        float vals[24];
        #pragma unroll
        for (int l = 0; l < 12; ++l) {
          vals[2*l]   = (own[l]      + yn[l]      - sum[l])      * ev;
          vals[2*l+1] = (own[12 + l] + yn[12 + l] - sum[12 + l]) * ev;
        }
        __syncthreads();                       // all o/y/e reads done
        float* vstg = (float*)smem;            // overlays x + front of o (24,576 B)
        f32x4* vw = (f32x4*)(vstg + r * 96 + pp * 24);
        #pragma unroll
        for (int i = 0; i < 6; ++i) {
          f32x4 t; t[0]=vals[4*i]; t[1]=vals[4*i+1]; t[2]=vals[4*i+2]; t[3]=vals[4*i+3];
          vw[i] = t;
        }
        __syncthreads();
        const f32x4* vp = (const f32x4*)vstg;
        f32x4* og = (f32x4*)(out + r0 * 96);
        #pragma unroll
        for (int i = 0; i < 6; ++i) og[tid + 256 * i] = vp[tid + 256 * i];
      }
    }
  }
}

extern "C" void kernel_launch(void* const* d_in, const int* in_sizes, int n_in,
                              void* d_out, int out_size, void* d_ws, size_t ws_size,
                              hipStream_t stream) {
  const float* y_real = (const float*)d_in[0];
  const float* y_imag = (const float*)d_in[1];
  const float* W1 = (const float*)d_in[2];
  const float* b1 = (const float*)d_in[3];
  const float* W2 = (const float*)d_in[4];
  const float* b2 = (const float*)d_in[5];
  const float* W3 = (const float*)d_in[6];
  const float* b3 = (const float*)d_in[7];
  float* out = (float*)d_out;
  u32x4* ws = (u32x4*)d_ws;   // needs 24*19*64*16 = 466,944 B

  hipLaunchKernelGGL(wpack, dim3(24), dim3(64), 0, stream,
                     W1, b1, W2, b2, W3, b3, ws);
  hipLaunchKernelGGL(rrsep, dim3(NB), dim3(256), 0, stream,
                     y_real, y_imag, ws, out);
}